// Round 3
// baseline (723.223 us; speedup 1.0000x reference)
//
#include <hip/hip_runtime.h>
#include <hip/hip_bf16.h>

#define HIDDEN 128
#define NPB 32   // nodes per block in conv GEMM

typedef __attribute__((ext_vector_type(8))) short s16x8;
typedef __attribute__((ext_vector_type(4))) short s16x4;
typedef __attribute__((ext_vector_type(4))) float f32x4;
typedef __attribute__((ext_vector_type(8))) __bf16 bf16x8;

__device__ __forceinline__ short f2bf(float x) {
    unsigned u = __float_as_uint(x);
    unsigned r = (u + 0x7fffu + ((u >> 16) & 1u)) >> 16;   // round-to-nearest-even
    return (short)r;
}
__device__ __forceinline__ float bf2f(short s) {
    return __uint_as_float(((unsigned)(unsigned short)s) << 16);
}

__device__ __forceinline__ void fma4(float4& acc, float s, const float4& w) {
    acc.x += s * w.x; acc.y += s * w.y; acc.z += s * w.z; acc.w += s * w.w;
}

// ---------------- weight transpose (once per launch, tiny) ----------------
// W1t/W2t: [256][128], rows 0..127 from W_l (k index), 128..255 from W_r
__global__ void k_transpose(const float* __restrict__ W1_l, const float* __restrict__ W1_r,
                            const float* __restrict__ W2_l, const float* __restrict__ W2_r,
                            float* __restrict__ W1t, float* __restrict__ W2t) {
    int idx = blockIdx.x * blockDim.x + threadIdx.x;
    if (idx < 256 * 128) {
        int k = idx >> 7, o = idx & 127;
        W1t[idx] = (k < 128) ? W1_l[o * 128 + k] : W1_r[o * 128 + (k - 128)];
        W2t[idx] = (k < 128) ? W2_l[o * 128 + k] : W2_r[o * 128 + (k - 128)];
    }
}

// ---------------- pack Wm1 into MFMA b-fragment order, split hi/lo bf16 ----
// Bh/Bl layout: [(s*8 + t)*64 + lane] -> 8 bf16 (k-contiguous), s=kstep(9), t=ntile(8)
// b_row n = t*16 + (lane&15); k = s*32 + (lane>>4)*8 + j ; k>=272 zero-padded
__global__ void k_packw(const float* __restrict__ Wm1, short* __restrict__ Bh,
                        short* __restrict__ Bl) {
    int idx = blockIdx.x * blockDim.x + threadIdx.x;   // 9*8*64 = 4608
    if (idx >= 9 * 8 * 64) return;
    int l = idx & 63;
    int t = (idx >> 6) & 7;
    int s = idx >> 9;
    int n = t * 16 + (l & 15);
    int kbase = s * 32 + (l >> 4) * 8;
    s16x8 h, lo;
    #pragma unroll
    for (int j = 0; j < 8; ++j) {
        int k = kbase + j;
        float v = (k < 272) ? Wm1[n * 272 + k] : 0.f;
        short hs = f2bf(v);
        h[j] = hs;
        lo[j] = f2bf(v - bf2f(hs));
    }
    ((s16x8*)Bh)[idx] = h;
    ((s16x8*)Bl)[idx] = lo;
}

// ---------------- fp32 -> split bf16 hi/lo (for h2 and pred_edge_attr) -----
__global__ void k_split(const float* __restrict__ in, short* __restrict__ hi,
                        short* __restrict__ lo, int n4) {   // n4 = n/4
    int i = blockIdx.x * blockDim.x + threadIdx.x;
    if (i >= n4) return;
    float4 v = ((const float4*)in)[i];
    s16x4 h, l;
    h[0] = f2bf(v.x); l[0] = f2bf(v.x - bf2f(h[0]));
    h[1] = f2bf(v.y); l[1] = f2bf(v.y - bf2f(h[1]));
    h[2] = f2bf(v.z); l[2] = f2bf(v.z - bf2f(h[2]));
    h[3] = f2bf(v.w); l[3] = f2bf(v.w - bf2f(h[3]));
    ((s16x4*)hi)[i] = h;
    ((s16x4*)lo)[i] = l;
}

// ---------------- CSR construction ----------------
__global__ void k_deg(const int* __restrict__ dst, int* __restrict__ deg, int n_edges) {
    for (int e = blockIdx.x * blockDim.x + threadIdx.x; e < n_edges; e += gridDim.x * blockDim.x)
        atomicAdd(&deg[dst[e]], 1);
}

// single-block exclusive scan; wave-shfl scan + cross-wave scan per 1024 chunk
__global__ __launch_bounds__(1024) void k_scan(const int* __restrict__ deg,
                                               int* __restrict__ row_start,
                                               int* __restrict__ cursor, int n) {
    __shared__ int wsum[16];
    __shared__ int s_running;
    int tid = threadIdx.x;
    int lane = tid & 63;
    int w = tid >> 6;   // 16 waves
    if (tid == 0) s_running = 0;
    __syncthreads();
    for (int base = 0; base < n; base += 1024) {
        int i = base + tid;
        int v = (i < n) ? deg[i] : 0;
        int s = v;
        #pragma unroll
        for (int off = 1; off < 64; off <<= 1) {
            int t = __shfl_up(s, off, 64);
            if (lane >= off) s += t;
        }
        if (lane == 63) wsum[w] = s;
        __syncthreads();
        if (w == 0) {
            int ws = (lane < 16) ? wsum[lane] : 0;
            #pragma unroll
            for (int off = 1; off < 16; off <<= 1) {
                int t = __shfl_up(ws, off, 64);
                if (lane >= off) ws += t;
            }
            if (lane < 16) wsum[lane] = ws;
        }
        __syncthreads();
        int incl = s + ((w > 0) ? wsum[w - 1] : 0);
        int excl = incl - v;
        int run = s_running;
        if (i < n) { row_start[i] = run + excl; cursor[i] = run + excl; }
        __syncthreads();
        if (tid == 1023) s_running = run + incl;
        __syncthreads();
    }
    if (threadIdx.x == 0) row_start[n] = s_running;
}

__global__ void k_fill(const int* __restrict__ src, const int* __restrict__ dst,
                       int* __restrict__ cursor, int* __restrict__ csr, int n_edges) {
    for (int e = blockIdx.x * blockDim.x + threadIdx.x; e < n_edges; e += gridDim.x * blockDim.x) {
        int d = dst[e];
        int p = atomicAdd(&cursor[d], 1);
        csr[p] = src[e];
    }
}

// ---------------- mean aggregation over CSR ----------------
// one 64-lane wave per node; lane owns features [2*lane, 2*lane+1] as float2
__global__ __launch_bounds__(256) void k_agg(const float* __restrict__ feat,
                                             const int* __restrict__ row_start,
                                             const int* __restrict__ csr,
                                             float* __restrict__ mean, int n_nodes) {
    int wave = (blockIdx.x * 256 + threadIdx.x) >> 6;
    if (wave >= n_nodes) return;
    int lane = threadIdx.x & 63;
    int s = row_start[wave], e = row_start[wave + 1];
    const float2* f2 = (const float2*)feat;
    float2 acc = make_float2(0.f, 0.f);
    for (int j = s; j < e; ++j) {
        int nb = csr[j];
        float2 v = f2[nb * 64 + lane];
        acc.x += v.x; acc.y += v.y;
    }
    float inv = (e > s) ? 1.0f / (float)(e - s) : 0.0f;
    ((float2*)mean)[wave * 64 + lane] = make_float2(acc.x * inv, acc.y * inv);
}

// ---------------- SAGE conv GEMM: out = relu([mean,h] @ Wt + b) ----------------
__global__ __launch_bounds__(256) void k_conv(const float* __restrict__ mean,
                                              const float* __restrict__ hin,
                                              const float* __restrict__ Wt,
                                              const float* __restrict__ bias,
                                              float* __restrict__ outp, int n_nodes) {
    __shared__ float a[NPB][256];
    int node0 = blockIdx.x * NPB;
    int tid = threadIdx.x;
    const float4* mean4 = (const float4*)mean;
    const float4* hin4  = (const float4*)hin;
    for (int i = tid; i < NPB * 64; i += 256) {
        int n = i >> 6, c4 = i & 63;
        int node = node0 + n;
        float4 v = make_float4(0.f, 0.f, 0.f, 0.f);
        if (node < n_nodes)
            v = (c4 < 32) ? mean4[node * 32 + c4] : hin4[node * 32 + (c4 - 32)];
        *(float4*)&a[n][c4 << 2] = v;
    }
    __syncthreads();
    int o4 = tid & 31;
    int ng = tid >> 5;
    float4 acc[4];
    #pragma unroll
    for (int n = 0; n < 4; ++n) acc[n] = make_float4(0.f, 0.f, 0.f, 0.f);
    const float4* W4 = (const float4*)Wt;  // [256][32] float4
    for (int k = 0; k < 256; k += 4) {
        float4 w0 = W4[(k + 0) * 32 + o4];
        float4 w1 = W4[(k + 1) * 32 + o4];
        float4 w2 = W4[(k + 2) * 32 + o4];
        float4 w3 = W4[(k + 3) * 32 + o4];
        #pragma unroll
        for (int n = 0; n < 4; ++n) {
            const float4 av = *(const float4*)&a[(ng << 2) + n][k];
            fma4(acc[n], av.x, w0);
            fma4(acc[n], av.y, w1);
            fma4(acc[n], av.z, w2);
            fma4(acc[n], av.w, w3);
        }
    }
    float4 b4 = ((const float4*)bias)[o4];
    #pragma unroll
    for (int n = 0; n < 4; ++n) {
        int node = node0 + (ng << 2) + n;
        if (node < n_nodes) {
            float4 r;
            r.x = fmaxf(acc[n].x + b4.x, 0.f);
            r.y = fmaxf(acc[n].y + b4.y, 0.f);
            r.z = fmaxf(acc[n].z + b4.z, 0.f);
            r.w = fmaxf(acc[n].w + b4.w, 0.f);
            ((float4*)outp)[node * 32 + o4] = r;
        }
    }
}

// ---------------- edge MLP via split-bf16 MFMA ----------------
// 64 edges/block, 256 threads (4 waves). Z[64][288] staged hi/lo in LDS.
// Wave w owns n-cols [w*32, w*32+32): ntiles 2w, 2w+1. acc: 4 mtiles x 2 ntiles.
__global__ __launch_bounds__(256) void k_mlp_mfma(
    const short* __restrict__ h2h, const short* __restrict__ h2l,
    const int* __restrict__ ps, const int* __restrict__ pd,
    const short* __restrict__ ath, const short* __restrict__ atl,
    const short* __restrict__ Bh, const short* __restrict__ Bl,
    const float* __restrict__ bm1, const float* __restrict__ wm2,
    const float* __restrict__ bm2, float* __restrict__ outp, int n_edges) {
    __shared__ __align__(16) short Ah[64][296];   // 296 = 288 + 8 pad (bank spread)
    __shared__ __align__(16) short Al[64][296];
    __shared__ float red[4][64];
    __shared__ int idx_s[64], idx_d[64];
    int tid = threadIdx.x;
    int e0 = blockIdx.x * 64;

    if (tid < 64) {
        int e = e0 + tid;
        int ok = (e < n_edges);
        idx_s[tid] = ok ? ps[e] : 0;
        idx_d[tid] = ok ? pd[e] : 0;
    }
    __syncthreads();

    // stage h-parts: 64 rows x 32 groups of 8 bf16 (cols 0..255)
    const s16x8* h2h8 = (const s16x8*)h2h;
    const s16x8* h2l8 = (const s16x8*)h2l;
    for (int i = tid; i < 64 * 32; i += 256) {
        int row = i >> 5, g = i & 31;
        int node = (g < 16) ? idx_s[row] : idx_d[row];
        int gg = g & 15;
        *(s16x8*)&Ah[row][g * 8] = h2h8[node * 16 + gg];
        *(s16x8*)&Al[row][g * 8] = h2l8[node * 16 + gg];
    }
    // attr (cols 256..271) + zero pad (272..287): groups 32..35
    const s16x8* ath8 = (const s16x8*)ath;
    const s16x8* atl8 = (const s16x8*)atl;
    for (int i = tid; i < 64 * 4; i += 256) {
        int row = i >> 2, g = 32 + (i & 3);
        int e = e0 + row;
        s16x8 vh = 0, vl = 0;
        if (g < 34 && e < n_edges) {
            vh = ath8[e * 2 + (g - 32)];
            vl = atl8[e * 2 + (g - 32)];
        }
        *(s16x8*)&Ah[row][g * 8] = vh;
        *(s16x8*)&Al[row][g * 8] = vl;
    }
    __syncthreads();

    int lane = tid & 63;
    int w = tid >> 6;
    int rowid = lane & 15;
    int g = lane >> 4;
    int t0 = w * 2;

    f32x4 acc[4][2];
    #pragma unroll
    for (int m = 0; m < 4; ++m) {
        acc[m][0] = (f32x4)0.f;
        acc[m][1] = (f32x4)0.f;
    }

    const bf16x8* Bh8 = (const bf16x8*)Bh;
    const bf16x8* Bl8 = (const bf16x8*)Bl;
    bf16x8 bh0 = Bh8[(t0) * 64 + lane];
    bf16x8 bh1 = Bh8[(t0 + 1) * 64 + lane];
    bf16x8 bl0 = Bl8[(t0) * 64 + lane];
    bf16x8 bl1 = Bl8[(t0 + 1) * 64 + lane];

    #pragma unroll
    for (int s = 0; s < 9; ++s) {
        bf16x8 nh0 = bh0, nh1 = bh1, nl0 = bl0, nl1 = bl1;
        if (s < 8) {   // prefetch next k-step's B fragments
            nh0 = Bh8[((s + 1) * 8 + t0) * 64 + lane];
            nh1 = Bh8[((s + 1) * 8 + t0 + 1) * 64 + lane];
            nl0 = Bl8[((s + 1) * 8 + t0) * 64 + lane];
            nl1 = Bl8[((s + 1) * 8 + t0 + 1) * 64 + lane];
        }
        int kf = s * 32 + g * 8;
        bf16x8 a_h[4], a_l[4];
        #pragma unroll
        for (int m = 0; m < 4; ++m) {
            a_h[m] = *(const bf16x8*)&Ah[m * 16 + rowid][kf];
            a_l[m] = *(const bf16x8*)&Al[m * 16 + rowid][kf];
        }
        #pragma unroll
        for (int m = 0; m < 4; ++m) {
            acc[m][0] = __builtin_amdgcn_mfma_f32_16x16x32_bf16(a_h[m], bh0, acc[m][0], 0, 0, 0);
            acc[m][1] = __builtin_amdgcn_mfma_f32_16x16x32_bf16(a_h[m], bh1, acc[m][1], 0, 0, 0);
            acc[m][0] = __builtin_amdgcn_mfma_f32_16x16x32_bf16(a_l[m], bh0, acc[m][0], 0, 0, 0);
            acc[m][1] = __builtin_amdgcn_mfma_f32_16x16x32_bf16(a_l[m], bh1, acc[m][1], 0, 0, 0);
            acc[m][0] = __builtin_amdgcn_mfma_f32_16x16x32_bf16(a_h[m], bl0, acc[m][0], 0, 0, 0);
            acc[m][1] = __builtin_amdgcn_mfma_f32_16x16x32_bf16(a_h[m], bl1, acc[m][1], 0, 0, 0);
        }
        bh0 = nh0; bh1 = nh1; bl0 = nl0; bl1 = nl1;
    }

    // epilogue: out[e] = sum_n relu(D[m][n] + bm1[n]) * wm2[n] + bm2
    // C/D layout (m89-verified): col = lane&15 (n within tile), row = g*4 + reg (m within tile)
    int n0 = w * 32 + rowid;
    int n1 = n0 + 16;
    float bm1_0 = bm1[n0], bm1_1 = bm1[n1];
    float wm2_0 = wm2[n0], wm2_1 = wm2[n1];
    #pragma unroll
    for (int m = 0; m < 4; ++m) {
        #pragma unroll
        for (int r = 0; r < 4; ++r) {
            float v = fmaxf(acc[m][0][r] + bm1_0, 0.f) * wm2_0
                    + fmaxf(acc[m][1][r] + bm1_1, 0.f) * wm2_1;
            v += __shfl_xor(v, 8, 16);
            v += __shfl_xor(v, 4, 16);
            v += __shfl_xor(v, 2, 16);
            v += __shfl_xor(v, 1, 16);
            if (rowid == 0) red[w][m * 16 + g * 4 + r] = v;
        }
    }
    __syncthreads();
    if (tid < 64) {
        int e = e0 + tid;
        if (e < n_edges)
            outp[e] = red[0][tid] + red[1][tid] + red[2][tid] + red[3][tid] + bm2[0];
    }
}

extern "C" void kernel_launch(void* const* d_in, const int* in_sizes, int n_in,
                              void* d_out, int out_size, void* d_ws, size_t ws_size,
                              hipStream_t stream) {
    const float* x     = (const float*)d_in[0];
    const int*   mp    = (const int*)d_in[1];
    const int*   pe    = (const int*)d_in[2];
    const float* attr  = (const float*)d_in[3];
    const float* W1_l  = (const float*)d_in[4];
    const float* b1    = (const float*)d_in[5];
    const float* W1_r  = (const float*)d_in[6];
    const float* W2_l  = (const float*)d_in[7];
    const float* b2    = (const float*)d_in[8];
    const float* W2_r  = (const float*)d_in[9];
    const float* Wm1   = (const float*)d_in[10];
    const float* bm1   = (const float*)d_in[11];
    const float* Wm2   = (const float*)d_in[12];
    const float* bm2   = (const float*)d_in[13];
    float* out = (float*)d_out;

    const int n_nodes = in_sizes[0] / HIDDEN;   // 50000
    const int n_mp    = in_sizes[1] / 2;        // 800000
    const int n_pred  = in_sizes[2] / 2;        // 400000

    const int* mp_src = mp;
    const int* mp_dst = mp + n_mp;
    const int* p_src  = pe;
    const int* p_dst  = pe + n_pred;

    // workspace layout
    char* ws = (char*)d_ws;
    size_t off = 0;
    auto alloc = [&](size_t bytes) -> void* {
        void* p = ws + off;
        off += (bytes + 255) & ~(size_t)255;
        return p;
    };
    float* W1t    = (float*)alloc(256 * 128 * sizeof(float));
    float* W2t    = (float*)alloc(256 * 128 * sizeof(float));
    short* Bh     = (short*)alloc(9 * 8 * 64 * 8 * sizeof(short));
    short* Bl     = (short*)alloc(9 * 8 * 64 * 8 * sizeof(short));
    int*   deg    = (int*)alloc((size_t)n_nodes * sizeof(int));
    int*   rowst  = (int*)alloc(((size_t)n_nodes + 1) * sizeof(int));
    int*   cursor = (int*)alloc((size_t)n_nodes * sizeof(int));
    int*   csr    = (int*)alloc((size_t)n_mp * sizeof(int));
    float* meanb  = (float*)alloc((size_t)n_nodes * HIDDEN * sizeof(float));
    float* h1     = (float*)alloc((size_t)n_nodes * HIDDEN * sizeof(float));
    float* h2     = (float*)alloc((size_t)n_nodes * HIDDEN * sizeof(float));
    short* h2h    = (short*)alloc((size_t)n_nodes * HIDDEN * sizeof(short));
    short* h2l    = (short*)alloc((size_t)n_nodes * HIDDEN * sizeof(short));
    short* ath    = (short*)alloc((size_t)n_pred * 16 * sizeof(short));
    short* atl    = (short*)alloc((size_t)n_pred * 16 * sizeof(short));
    (void)ws_size; (void)n_in; (void)out_size;

    // 0. zero degree counters
    hipMemsetAsync(deg, 0, (size_t)n_nodes * sizeof(int), stream);

    // 1. weight prep
    k_transpose<<<(256 * 128 + 255) / 256, 256, 0, stream>>>(W1_l, W1_r, W2_l, W2_r, W1t, W2t);
    k_packw<<<(9 * 8 * 64 + 255) / 256, 256, 0, stream>>>(Wm1, Bh, Bl);
    k_split<<<(n_pred * 16 / 4 + 255) / 256, 256, 0, stream>>>(attr, ath, atl, n_pred * 16 / 4);

    // 2. CSR build
    k_deg<<<(n_mp + 255) / 256, 256, 0, stream>>>(mp_dst, deg, n_mp);
    k_scan<<<1, 1024, 0, stream>>>(deg, rowst, cursor, n_nodes);
    k_fill<<<(n_mp + 255) / 256, 256, 0, stream>>>(mp_src, mp_dst, cursor, csr, n_mp);

    // 3. conv1
    k_agg<<<(n_nodes + 3) / 4, 256, 0, stream>>>(x, rowst, csr, meanb, n_nodes);
    k_conv<<<(n_nodes + NPB - 1) / NPB, 256, 0, stream>>>(meanb, x, W1t, b1, h1, n_nodes);

    // 4. conv2
    k_agg<<<(n_nodes + 3) / 4, 256, 0, stream>>>(h1, rowst, csr, meanb, n_nodes);
    k_conv<<<(n_nodes + NPB - 1) / NPB, 256, 0, stream>>>(meanb, h1, W2t, b2, h2, n_nodes);

    // 5. split h2 to bf16 hi/lo
    k_split<<<((size_t)n_nodes * HIDDEN / 4 + 255) / 256, 256, 0, stream>>>(
        h2, h2h, h2l, n_nodes * HIDDEN / 4);

    // 6. edge MLP (MFMA)
    k_mlp_mfma<<<(n_pred + 63) / 64, 256, 0, stream>>>(h2h, h2l, p_src, p_dst, ath, atl,
                                                       Bh, Bl, bm1, Wm2, bm2, out, n_pred);
}

// Round 4
// 635.152 us; speedup vs baseline: 1.1387x; 1.1387x over previous
//
#include <hip/hip_runtime.h>
#include <hip/hip_bf16.h>

#define HIDDEN 128

typedef __attribute__((ext_vector_type(8))) short s16x8;
typedef __attribute__((ext_vector_type(4))) short s16x4;
typedef __attribute__((ext_vector_type(4))) float f32x4;
typedef __attribute__((ext_vector_type(8))) __bf16 bf16x8;

__device__ __forceinline__ short f2bf(float x) {
    unsigned u = __float_as_uint(x);
    unsigned r = (u + 0x7fffu + ((u >> 16) & 1u)) >> 16;   // round-to-nearest-even
    return (short)r;
}
__device__ __forceinline__ float bf2f(short s) {
    return __uint_as_float(((unsigned)(unsigned short)s) << 16);
}

// ---------------- fp32 -> interleaved (hi,lo) bf16 pairs ----------------
// float4 -> 8 shorts (h0,l0,h1,l1,h2,l2,h3,l3)
__global__ void k_split(const float* __restrict__ in, short* __restrict__ outx, int n4) {
    int i = blockIdx.x * blockDim.x + threadIdx.x;
    if (i >= n4) return;
    float4 v = ((const float4*)in)[i];
    s16x8 o;
    o[0] = f2bf(v.x); o[1] = f2bf(v.x - bf2f(o[0]));
    o[2] = f2bf(v.y); o[3] = f2bf(v.y - bf2f(o[2]));
    o[4] = f2bf(v.z); o[5] = f2bf(v.z - bf2f(o[4]));
    o[6] = f2bf(v.w); o[7] = f2bf(v.w - bf2f(o[6]));
    ((s16x8*)outx)[i] = o;
}

// ---------------- pack conv weights into MFMA b-frag order, hi/lo ----------
// K=256: k<128 from Wl, else Wr. Bh/Bl[(s*8+t)*64+lane] = 8 k-contig bf16.
// n = t*16+(lane&15); k = s*32+(lane>>4)*8+j
__global__ void k_packw_conv(const float* __restrict__ Wl, const float* __restrict__ Wr,
                             short* __restrict__ Bh, short* __restrict__ Bl) {
    int idx = blockIdx.x * blockDim.x + threadIdx.x;   // 8*8*64 = 4096
    if (idx >= 8 * 8 * 64) return;
    int l = idx & 63;
    int t = (idx >> 6) & 7;
    int s = idx >> 9;
    int n = t * 16 + (l & 15);
    int kbase = s * 32 + (l >> 4) * 8;
    s16x8 h, lo;
    #pragma unroll
    for (int j = 0; j < 8; ++j) {
        int k = kbase + j;
        float v = (k < 128) ? Wl[n * 128 + k] : Wr[n * 128 + (k - 128)];
        short hs = f2bf(v);
        h[j] = hs;
        lo[j] = f2bf(v - bf2f(hs));
    }
    ((s16x8*)Bh)[idx] = h;
    ((s16x8*)Bl)[idx] = lo;
}

// ---------------- pack Wm1 (K=272, padded to 288) ----------
__global__ void k_packw_mlp(const float* __restrict__ Wm1, short* __restrict__ Bh,
                            short* __restrict__ Bl) {
    int idx = blockIdx.x * blockDim.x + threadIdx.x;   // 9*8*64 = 4608
    if (idx >= 9 * 8 * 64) return;
    int l = idx & 63;
    int t = (idx >> 6) & 7;
    int s = idx >> 9;
    int n = t * 16 + (l & 15);
    int kbase = s * 32 + (l >> 4) * 8;
    s16x8 h, lo;
    #pragma unroll
    for (int j = 0; j < 8; ++j) {
        int k = kbase + j;
        float v = (k < 272) ? Wm1[n * 272 + k] : 0.f;
        short hs = f2bf(v);
        h[j] = hs;
        lo[j] = f2bf(v - bf2f(hs));
    }
    ((s16x8*)Bh)[idx] = h;
    ((s16x8*)Bl)[idx] = lo;
}

// ---------------- CSR construction ----------------
__global__ void k_deg(const int* __restrict__ dst, int* __restrict__ deg, int n_edges) {
    for (int e = blockIdx.x * blockDim.x + threadIdx.x; e < n_edges; e += gridDim.x * blockDim.x)
        atomicAdd(&deg[dst[e]], 1);
}

__global__ __launch_bounds__(1024) void k_scan(const int* __restrict__ deg,
                                               int* __restrict__ row_start,
                                               int* __restrict__ cursor, int n) {
    __shared__ int wsum[16];
    __shared__ int s_running;
    int tid = threadIdx.x;
    int lane = tid & 63;
    int w = tid >> 6;   // 16 waves
    if (tid == 0) s_running = 0;
    __syncthreads();
    for (int base = 0; base < n; base += 1024) {
        int i = base + tid;
        int v = (i < n) ? deg[i] : 0;
        int s = v;
        #pragma unroll
        for (int off = 1; off < 64; off <<= 1) {
            int t = __shfl_up(s, off, 64);
            if (lane >= off) s += t;
        }
        if (lane == 63) wsum[w] = s;
        __syncthreads();
        if (w == 0) {
            int ws = (lane < 16) ? wsum[lane] : 0;
            #pragma unroll
            for (int off = 1; off < 16; off <<= 1) {
                int t = __shfl_up(ws, off, 64);
                if (lane >= off) ws += t;
            }
            if (lane < 16) wsum[lane] = ws;
        }
        __syncthreads();
        int incl = s + ((w > 0) ? wsum[w - 1] : 0);
        int excl = incl - v;
        int run = s_running;
        if (i < n) { row_start[i] = run + excl; cursor[i] = run + excl; }
        __syncthreads();
        if (tid == 1023) s_running = run + incl;
        __syncthreads();
    }
    if (threadIdx.x == 0) row_start[n] = s_running;
}

__global__ void k_fill(const int* __restrict__ src, const int* __restrict__ dst,
                       int* __restrict__ cursor, int* __restrict__ csr, int n_edges) {
    for (int e = blockIdx.x * blockDim.x + threadIdx.x; e < n_edges; e += gridDim.x * blockDim.x) {
        int d = dst[e];
        int p = atomicAdd(&cursor[d], 1);
        csr[p] = src[e];
    }
}

// ---------------- mean aggregation (fp32 input) -> interleaved split out ----
// one 64-lane wave per node; lane owns features 2*lane, 2*lane+1
__global__ __launch_bounds__(256) void k_agg_f32(const float* __restrict__ feat,
                                                 const int* __restrict__ row_start,
                                                 const int* __restrict__ csr,
                                                 short* __restrict__ outx, int n_nodes) {
    int wave = (blockIdx.x * 256 + threadIdx.x) >> 6;
    if (wave >= n_nodes) return;
    int lane = threadIdx.x & 63;
    int s = row_start[wave], e = row_start[wave + 1];
    const float2* f2p = (const float2*)feat;
    float ax = 0.f, ay = 0.f;
    for (int j = s; j < e; ++j) {
        int nb = csr[j];
        float2 v = f2p[nb * 64 + lane];
        ax += v.x; ay += v.y;
    }
    float inv = (e > s) ? 1.0f / (float)(e - s) : 0.0f;
    float m0 = ax * inv, m1 = ay * inv;
    s16x4 o;
    o[0] = f2bf(m0); o[1] = f2bf(m0 - bf2f(o[0]));
    o[2] = f2bf(m1); o[3] = f2bf(m1 - bf2f(o[2]));
    ((s16x4*)outx)[wave * 64 + lane] = o;
}

// ---------------- mean aggregation (interleaved split input) ----------------
__global__ __launch_bounds__(256) void k_agg_ix(const short* __restrict__ featx,
                                                const int* __restrict__ row_start,
                                                const int* __restrict__ csr,
                                                short* __restrict__ outx, int n_nodes) {
    int wave = (blockIdx.x * 256 + threadIdx.x) >> 6;
    if (wave >= n_nodes) return;
    int lane = threadIdx.x & 63;
    int s = row_start[wave], e = row_start[wave + 1];
    const s16x4* fx = (const s16x4*)featx;
    float ax = 0.f, ay = 0.f;
    for (int j = s; j < e; ++j) {
        int nb = csr[j];
        s16x4 q = fx[nb * 64 + lane];
        ax += bf2f(q[0]) + bf2f(q[1]);
        ay += bf2f(q[2]) + bf2f(q[3]);
    }
    float inv = (e > s) ? 1.0f / (float)(e - s) : 0.0f;
    float m0 = ax * inv, m1 = ay * inv;
    s16x4 o;
    o[0] = f2bf(m0); o[1] = f2bf(m0 - bf2f(o[0]));
    o[2] = f2bf(m1); o[3] = f2bf(m1 - bf2f(o[2]));
    ((s16x4*)outx)[wave * 64 + lane] = o;
}

// ---------------- SAGE conv via split-bf16 MFMA ----------------
// 32 nodes/block, 256 thr (4 waves x 2 ntiles). A=[mean|root] K=256 (8 ksteps).
// out: relu -> split hi/lo -> interleaved table.
__global__ __launch_bounds__(256, 4) void k_convm(
    const short* __restrict__ mx, const short* __restrict__ rootx,
    const short* __restrict__ Bh, const short* __restrict__ Bl,
    const float* __restrict__ bias, short* __restrict__ outx, int n_nodes) {
    __shared__ __align__(16) short Ah[32][264];
    __shared__ __align__(16) short Al[32][264];
    int tid = threadIdx.x;
    int node0 = blockIdx.x * 32;
    const s16x8* mx8 = (const s16x8*)mx;
    const s16x8* rt8 = (const s16x8*)rootx;
    for (int i = tid; i < 32 * 64; i += 256) {
        int row = i >> 6, grp = i & 63;
        int node = node0 + row;
        s16x8 v = (s16x8)0;
        if (node < n_nodes)
            v = (grp < 32) ? mx8[node * 32 + grp] : rt8[node * 32 + (grp - 32)];
        s16x4 h, l;
        h[0] = v[0]; h[1] = v[2]; h[2] = v[4]; h[3] = v[6];
        l[0] = v[1]; l[1] = v[3]; l[2] = v[5]; l[3] = v[7];
        *(s16x4*)&Ah[row][grp * 4] = h;
        *(s16x4*)&Al[row][grp * 4] = l;
    }
    __syncthreads();

    int lane = tid & 63;
    int w = tid >> 6;
    int rowid = lane & 15;
    int g = lane >> 4;
    int t0 = w * 2;

    f32x4 acc[2][2];
    acc[0][0] = (f32x4)0.f; acc[0][1] = (f32x4)0.f;
    acc[1][0] = (f32x4)0.f; acc[1][1] = (f32x4)0.f;

    const bf16x8* Bh8 = (const bf16x8*)Bh;
    const bf16x8* Bl8 = (const bf16x8*)Bl;
    bf16x8 bh0 = Bh8[t0 * 64 + lane];
    bf16x8 bh1 = Bh8[(t0 + 1) * 64 + lane];
    bf16x8 bl0 = Bl8[t0 * 64 + lane];
    bf16x8 bl1 = Bl8[(t0 + 1) * 64 + lane];

    #pragma unroll
    for (int s = 0; s < 8; ++s) {
        bf16x8 nh0 = bh0, nh1 = bh1, nl0 = bl0, nl1 = bl1;
        if (s < 7) {
            nh0 = Bh8[((s + 1) * 8 + t0) * 64 + lane];
            nh1 = Bh8[((s + 1) * 8 + t0 + 1) * 64 + lane];
            nl0 = Bl8[((s + 1) * 8 + t0) * 64 + lane];
            nl1 = Bl8[((s + 1) * 8 + t0 + 1) * 64 + lane];
        }
        int kf = s * 32 + g * 8;
        bf16x8 a_h[2], a_l[2];
        #pragma unroll
        for (int m = 0; m < 2; ++m) {
            a_h[m] = *(const bf16x8*)&Ah[m * 16 + rowid][kf];
            a_l[m] = *(const bf16x8*)&Al[m * 16 + rowid][kf];
        }
        #pragma unroll
        for (int m = 0; m < 2; ++m) {
            acc[m][0] = __builtin_amdgcn_mfma_f32_16x16x32_bf16(a_h[m], bh0, acc[m][0], 0, 0, 0);
            acc[m][1] = __builtin_amdgcn_mfma_f32_16x16x32_bf16(a_h[m], bh1, acc[m][1], 0, 0, 0);
            acc[m][0] = __builtin_amdgcn_mfma_f32_16x16x32_bf16(a_l[m], bh0, acc[m][0], 0, 0, 0);
            acc[m][1] = __builtin_amdgcn_mfma_f32_16x16x32_bf16(a_l[m], bh1, acc[m][1], 0, 0, 0);
            acc[m][0] = __builtin_amdgcn_mfma_f32_16x16x32_bf16(a_h[m], bl0, acc[m][0], 0, 0, 0);
            acc[m][1] = __builtin_amdgcn_mfma_f32_16x16x32_bf16(a_h[m], bl1, acc[m][1], 0, 0, 0);
        }
        bh0 = nh0; bh1 = nh1; bl0 = nl0; bl1 = nl1;
    }

    // epilogue: relu(D + b) -> hi/lo pair -> interleaved out
    // D: col(lane&15)=n within ntile, row(g*4+r)=node within mtile
    int n0 = w * 32 + rowid;
    int n1 = n0 + 16;
    float b_0 = bias[n0], b_1 = bias[n1];
    unsigned* outu = (unsigned*)outx;
    #pragma unroll
    for (int m = 0; m < 2; ++m) {
        int node = node0 + m * 16 + g * 4;
        #pragma unroll
        for (int r = 0; r < 4; ++r) {
            if (node + r < n_nodes) {
                float v0 = fmaxf(acc[m][0][r] + b_0, 0.f);
                float v1 = fmaxf(acc[m][1][r] + b_1, 0.f);
                short h0 = f2bf(v0), l0 = f2bf(v0 - bf2f(h0));
                short h1 = f2bf(v1), l1 = f2bf(v1 - bf2f(h1));
                outu[(node + r) * 128 + n0] = (unsigned)(unsigned short)h0 |
                                              ((unsigned)(unsigned short)l0 << 16);
                outu[(node + r) * 128 + n1] = (unsigned)(unsigned short)h1 |
                                              ((unsigned)(unsigned short)l1 << 16);
            }
        }
    }
}

// ---------------- edge MLP via split-bf16 MFMA (32 edges/block) ----------------
__global__ __launch_bounds__(256, 4) void k_mlp_mfma(
    const short* __restrict__ h2x, const int* __restrict__ ps, const int* __restrict__ pd,
    const short* __restrict__ atx, const short* __restrict__ Bh, const short* __restrict__ Bl,
    const float* __restrict__ bm1, const float* __restrict__ wm2,
    const float* __restrict__ bm2, float* __restrict__ outp, int n_edges) {
    __shared__ __align__(16) short Ah[32][296];
    __shared__ __align__(16) short Al[32][296];
    __shared__ float red[4][32];
    __shared__ int idx_s[32], idx_d[32];
    int tid = threadIdx.x;
    int e0 = blockIdx.x * 32;

    if (tid < 32) {
        int e = e0 + tid;
        int ok = (e < n_edges);
        idx_s[tid] = ok ? ps[e] : 0;
        idx_d[tid] = ok ? pd[e] : 0;
    }
    __syncthreads();

    const s16x8* h2x8 = (const s16x8*)h2x;
    const s16x8* atx8 = (const s16x8*)atx;
    // 32 rows x 72 groups (4 feats each): 0..31 src, 32..63 dst, 64..67 attr, 68..71 zero
    for (int i = tid; i < 32 * 72; i += 256) {
        int row = i / 72;
        int grp = i - row * 72;
        int e = e0 + row;
        s16x8 v = (s16x8)0;
        if (e < n_edges) {
            if (grp < 32)      v = h2x8[idx_s[row] * 32 + grp];
            else if (grp < 64) v = h2x8[idx_d[row] * 32 + (grp - 32)];
            else if (grp < 68) v = atx8[e * 4 + (grp - 64)];
        }
        s16x4 h, l;
        h[0] = v[0]; h[1] = v[2]; h[2] = v[4]; h[3] = v[6];
        l[0] = v[1]; l[1] = v[3]; l[2] = v[5]; l[3] = v[7];
        *(s16x4*)&Ah[row][grp * 4] = h;
        *(s16x4*)&Al[row][grp * 4] = l;
    }
    __syncthreads();

    int lane = tid & 63;
    int w = tid >> 6;
    int rowid = lane & 15;
    int g = lane >> 4;
    int t0 = w * 2;

    f32x4 acc[2][2];
    acc[0][0] = (f32x4)0.f; acc[0][1] = (f32x4)0.f;
    acc[1][0] = (f32x4)0.f; acc[1][1] = (f32x4)0.f;

    const bf16x8* Bh8 = (const bf16x8*)Bh;
    const bf16x8* Bl8 = (const bf16x8*)Bl;
    bf16x8 bh0 = Bh8[t0 * 64 + lane];
    bf16x8 bh1 = Bh8[(t0 + 1) * 64 + lane];
    bf16x8 bl0 = Bl8[t0 * 64 + lane];
    bf16x8 bl1 = Bl8[(t0 + 1) * 64 + lane];

    #pragma unroll
    for (int s = 0; s < 9; ++s) {
        bf16x8 nh0 = bh0, nh1 = bh1, nl0 = bl0, nl1 = bl1;
        if (s < 8) {
            nh0 = Bh8[((s + 1) * 8 + t0) * 64 + lane];
            nh1 = Bh8[((s + 1) * 8 + t0 + 1) * 64 + lane];
            nl0 = Bl8[((s + 1) * 8 + t0) * 64 + lane];
            nl1 = Bl8[((s + 1) * 8 + t0 + 1) * 64 + lane];
        }
        int kf = s * 32 + g * 8;
        bf16x8 a_h[2], a_l[2];
        #pragma unroll
        for (int m = 0; m < 2; ++m) {
            a_h[m] = *(const bf16x8*)&Ah[m * 16 + rowid][kf];
            a_l[m] = *(const bf16x8*)&Al[m * 16 + rowid][kf];
        }
        #pragma unroll
        for (int m = 0; m < 2; ++m) {
            acc[m][0] = __builtin_amdgcn_mfma_f32_16x16x32_bf16(a_h[m], bh0, acc[m][0], 0, 0, 0);
            acc[m][1] = __builtin_amdgcn_mfma_f32_16x16x32_bf16(a_h[m], bh1, acc[m][1], 0, 0, 0);
            acc[m][0] = __builtin_amdgcn_mfma_f32_16x16x32_bf16(a_l[m], bh0, acc[m][0], 0, 0, 0);
            acc[m][1] = __builtin_amdgcn_mfma_f32_16x16x32_bf16(a_l[m], bh1, acc[m][1], 0, 0, 0);
            acc[m][0] = __builtin_amdgcn_mfma_f32_16x16x32_bf16(a_h[m], bl0, acc[m][0], 0, 0, 0);
            acc[m][1] = __builtin_amdgcn_mfma_f32_16x16x32_bf16(a_h[m], bl1, acc[m][1], 0, 0, 0);
        }
        bh0 = nh0; bh1 = nh1; bl0 = nl0; bl1 = nl1;
    }

    // epilogue: out[e] = sum_n relu(D + bm1) * wm2 + bm2
    int n0 = w * 32 + rowid;
    int n1 = n0 + 16;
    float bm1_0 = bm1[n0], bm1_1 = bm1[n1];
    float wm2_0 = wm2[n0], wm2_1 = wm2[n1];
    #pragma unroll
    for (int m = 0; m < 2; ++m) {
        #pragma unroll
        for (int r = 0; r < 4; ++r) {
            float v = fmaxf(acc[m][0][r] + bm1_0, 0.f) * wm2_0
                    + fmaxf(acc[m][1][r] + bm1_1, 0.f) * wm2_1;
            v += __shfl_xor(v, 8, 16);
            v += __shfl_xor(v, 4, 16);
            v += __shfl_xor(v, 2, 16);
            v += __shfl_xor(v, 1, 16);
            if (rowid == 0) red[w][m * 16 + g * 4 + r] = v;
        }
    }
    __syncthreads();
    if (tid < 32) {
        int e = e0 + tid;
        if (e < n_edges)
            outp[e] = red[0][tid] + red[1][tid] + red[2][tid] + red[3][tid] + bm2[0];
    }
}

extern "C" void kernel_launch(void* const* d_in, const int* in_sizes, int n_in,
                              void* d_out, int out_size, void* d_ws, size_t ws_size,
                              hipStream_t stream) {
    const float* x     = (const float*)d_in[0];
    const int*   mp    = (const int*)d_in[1];
    const int*   pe    = (const int*)d_in[2];
    const float* attr  = (const float*)d_in[3];
    const float* W1_l  = (const float*)d_in[4];
    const float* b1    = (const float*)d_in[5];
    const float* W1_r  = (const float*)d_in[6];
    const float* W2_l  = (const float*)d_in[7];
    const float* b2    = (const float*)d_in[8];
    const float* W2_r  = (const float*)d_in[9];
    const float* Wm1   = (const float*)d_in[10];
    const float* bm1   = (const float*)d_in[11];
    const float* Wm2   = (const float*)d_in[12];
    const float* bm2   = (const float*)d_in[13];
    float* out = (float*)d_out;

    const int n_nodes = in_sizes[0] / HIDDEN;   // 50000
    const int n_mp    = in_sizes[1] / 2;        // 800000
    const int n_pred  = in_sizes[2] / 2;        // 400000

    const int* mp_src = mp;
    const int* mp_dst = mp + n_mp;
    const int* p_src  = pe;
    const int* p_dst  = pe + n_pred;

    // workspace layout
    char* ws = (char*)d_ws;
    size_t off = 0;
    auto alloc = [&](size_t bytes) -> void* {
        void* p = ws + off;
        off += (bytes + 255) & ~(size_t)255;
        return p;
    };
    short* Wc1h  = (short*)alloc(8 * 8 * 64 * 8 * sizeof(short));
    short* Wc1l  = (short*)alloc(8 * 8 * 64 * 8 * sizeof(short));
    short* Wc2h  = (short*)alloc(8 * 8 * 64 * 8 * sizeof(short));
    short* Wc2l  = (short*)alloc(8 * 8 * 64 * 8 * sizeof(short));
    short* Bmh   = (short*)alloc(9 * 8 * 64 * 8 * sizeof(short));
    short* Bml   = (short*)alloc(9 * 8 * 64 * 8 * sizeof(short));
    int*   deg    = (int*)alloc((size_t)n_nodes * sizeof(int));
    int*   rowst  = (int*)alloc(((size_t)n_nodes + 1) * sizeof(int));
    int*   cursor = (int*)alloc((size_t)n_nodes * sizeof(int));
    int*   csr    = (int*)alloc((size_t)n_mp * sizeof(int));
    short* xx     = (short*)alloc((size_t)n_nodes * 256 * sizeof(short));
    short* mx     = (short*)alloc((size_t)n_nodes * 256 * sizeof(short));
    short* h1x    = (short*)alloc((size_t)n_nodes * 256 * sizeof(short));
    short* h2x    = (short*)alloc((size_t)n_nodes * 256 * sizeof(short));
    short* atx    = (short*)alloc((size_t)n_pred * 32 * sizeof(short));
    (void)ws_size; (void)n_in; (void)out_size;

    // 0. zero degree counters
    hipMemsetAsync(deg, 0, (size_t)n_nodes * sizeof(int), stream);

    // 1. weight packing + input splits
    k_packw_conv<<<16, 256, 0, stream>>>(W1_l, W1_r, Wc1h, Wc1l);
    k_packw_conv<<<16, 256, 0, stream>>>(W2_l, W2_r, Wc2h, Wc2l);
    k_packw_mlp<<<18, 256, 0, stream>>>(Wm1, Bmh, Bml);
    k_split<<<(n_nodes * 32 + 255) / 256, 256, 0, stream>>>(x, xx, n_nodes * 32);
    k_split<<<(n_pred * 4 + 255) / 256, 256, 0, stream>>>(attr, atx, n_pred * 4);

    // 2. CSR build
    k_deg<<<(n_mp + 255) / 256, 256, 0, stream>>>(mp_dst, deg, n_mp);
    k_scan<<<1, 1024, 0, stream>>>(deg, rowst, cursor, n_nodes);
    k_fill<<<(n_mp + 255) / 256, 256, 0, stream>>>(mp_src, mp_dst, cursor, csr, n_mp);

    // 3. conv1: agg(x) -> mx; [mx|xx] @ W1 -> h1x
    k_agg_f32<<<(n_nodes + 3) / 4, 256, 0, stream>>>(x, rowst, csr, mx, n_nodes);
    k_convm<<<(n_nodes + 31) / 32, 256, 0, stream>>>(mx, xx, Wc1h, Wc1l, b1, h1x, n_nodes);

    // 4. conv2: agg(h1x) -> mx; [mx|h1x] @ W2 -> h2x
    k_agg_ix<<<(n_nodes + 3) / 4, 256, 0, stream>>>(h1x, rowst, csr, mx, n_nodes);
    k_convm<<<(n_nodes + 31) / 32, 256, 0, stream>>>(mx, h1x, Wc2h, Wc2l, b2, h2x, n_nodes);

    // 5. edge MLP (MFMA)
    k_mlp_mfma<<<(n_pred + 31) / 32, 256, 0, stream>>>(h2x, p_src, p_dst, atx,
                                                       Bmh, Bml, bm1, Wm2, bm2, out, n_pred);
}

// Round 6
// 550.075 us; speedup vs baseline: 1.3148x; 1.1547x over previous
//
#include <hip/hip_runtime.h>
#include <hip/hip_bf16.h>

#define HIDDEN 128

typedef __attribute__((ext_vector_type(8))) short s16x8;
typedef __attribute__((ext_vector_type(4))) short s16x4;
typedef __attribute__((ext_vector_type(4))) float f32x4;
typedef __attribute__((ext_vector_type(8))) __bf16 bf16x8;

__device__ __forceinline__ short f2bf(float x) {
    unsigned u = __float_as_uint(x);
    unsigned r = (u + 0x7fffu + ((u >> 16) & 1u)) >> 16;   // round-to-nearest-even
    return (short)r;
}
__device__ __forceinline__ float bf2f(short s) {
    return __uint_as_float(((unsigned)(unsigned short)s) << 16);
}

// ---------------- fp32 -> two bf16 tables (hi, lo) ----------------
__global__ void k_split(const float* __restrict__ in, short* __restrict__ hi,
                        short* __restrict__ lo, int n4) {
    int i = blockIdx.x * blockDim.x + threadIdx.x;
    if (i >= n4) return;
    float4 v = ((const float4*)in)[i];
    s16x4 h, l;
    h[0] = f2bf(v.x); l[0] = f2bf(v.x - bf2f(h[0]));
    h[1] = f2bf(v.y); l[1] = f2bf(v.y - bf2f(h[1]));
    h[2] = f2bf(v.z); l[2] = f2bf(v.z - bf2f(h[2]));
    h[3] = f2bf(v.w); l[3] = f2bf(v.w - bf2f(h[3]));
    ((s16x4*)hi)[i] = h;
    ((s16x4*)lo)[i] = l;
}

// ---------------- pack conv weights into MFMA b-frag order, hi/lo ----------
// K=256: k<128 from Wl, else Wr. B[(s*8+t)*64+lane] = 8 k-contig bf16.
// n = t*16+(lane&15); k = s*32+(lane>>4)*8+j
__global__ void k_packw_conv(const float* __restrict__ Wl, const float* __restrict__ Wr,
                             short* __restrict__ Bh, short* __restrict__ Bl) {
    int idx = blockIdx.x * blockDim.x + threadIdx.x;   // 8*8*64 = 4096
    if (idx >= 8 * 8 * 64) return;
    int l = idx & 63;
    int t = (idx >> 6) & 7;
    int s = idx >> 9;
    int n = t * 16 + (l & 15);
    int kbase = s * 32 + (l >> 4) * 8;
    s16x8 h, lo;
    #pragma unroll
    for (int j = 0; j < 8; ++j) {
        int k = kbase + j;
        float v = (k < 128) ? Wl[n * 128 + k] : Wr[n * 128 + (k - 128)];
        short hs = f2bf(v);
        h[j] = hs;
        lo[j] = f2bf(v - bf2f(hs));
    }
    ((s16x8*)Bh)[idx] = h;
    ((s16x8*)Bl)[idx] = lo;
}

// ---------------- pack [Wm1_src; Wm1_dst] for the UV GEMM ----------
// out n' in [0,256): n'<128 -> U row n' uses Wm1[n'][k]; n'>=128 -> V uses Wm1[n'-128][128+k]
// frag idx = (s*16 + t)*64 + lane, s=kstep(4), t=ntile(16)
__global__ void k_packw_uv(const float* __restrict__ Wm1, short* __restrict__ Bh,
                           short* __restrict__ Bl) {
    int idx = blockIdx.x * blockDim.x + threadIdx.x;   // 4*16*64 = 4096
    if (idx >= 4 * 16 * 64) return;
    int l = idx & 63;
    int t = (idx >> 6) & 15;
    int s = idx >> 10;
    int np = t * 16 + (l & 15);
    int kbase = s * 32 + (l >> 4) * 8;
    s16x8 h, lo;
    #pragma unroll
    for (int j = 0; j < 8; ++j) {
        int k = kbase + j;
        float v = (np < 128) ? Wm1[np * 272 + k] : Wm1[(np - 128) * 272 + 128 + k];
        short hs = f2bf(v);
        h[j] = hs;
        lo[j] = f2bf(v - bf2f(hs));
    }
    ((s16x8*)Bh)[idx] = h;
    ((s16x8*)Bl)[idx] = lo;
}

// ---------------- CSR construction ----------------
__global__ void k_deg(const int* __restrict__ dst, int* __restrict__ deg, int n_edges) {
    for (int e = blockIdx.x * blockDim.x + threadIdx.x; e < n_edges; e += gridDim.x * blockDim.x)
        atomicAdd(&deg[dst[e]], 1);
}

// block-local exclusive scan; part[b] = block total
__global__ __launch_bounds__(1024) void k_scan_blk(const int* __restrict__ deg,
                                                   int* __restrict__ row_start,
                                                   int* __restrict__ part, int n) {
    __shared__ int wsum[16];
    int tid = threadIdx.x;
    int lane = tid & 63;
    int w = tid >> 6;
    int i = blockIdx.x * 1024 + tid;
    int v = (i < n) ? deg[i] : 0;
    int s = v;
    #pragma unroll
    for (int off = 1; off < 64; off <<= 1) {
        int t = __shfl_up(s, off, 64);
        if (lane >= off) s += t;
    }
    if (lane == 63) wsum[w] = s;
    __syncthreads();
    if (w == 0) {
        int ws = (lane < 16) ? wsum[lane] : 0;
        #pragma unroll
        for (int off = 1; off < 16; off <<= 1) {
            int t = __shfl_up(ws, off, 64);
            if (lane >= off) ws += t;
        }
        if (lane < 16) wsum[lane] = ws;
    }
    __syncthreads();
    int incl = s + ((w > 0) ? wsum[w - 1] : 0);
    if (i < n) row_start[i] = incl - v;      // block-local exclusive
    if (tid == 1023) part[blockIdx.x] = incl; // block total
}

// single-wave scan of block partials (P <= 64)
__global__ void k_scan_top(int* __restrict__ part, int* __restrict__ row_start,
                           int P, int n) {
    int lane = threadIdx.x;
    int v = (lane < P) ? part[lane] : 0;
    int s = v;
    #pragma unroll
    for (int off = 1; off < 64; off <<= 1) {
        int t = __shfl_up(s, off, 64);
        if (lane >= off) s += t;
    }
    if (lane < P) part[lane] = s - v;        // exclusive block offset
    if (lane == P - 1) row_start[n] = s;     // grand total
}

__global__ __launch_bounds__(1024) void k_scan_add(int* __restrict__ row_start,
                                                   int* __restrict__ cursor,
                                                   const int* __restrict__ part, int n) {
    int i = blockIdx.x * 1024 + threadIdx.x;
    if (i < n) {
        int r = row_start[i] + part[blockIdx.x];
        row_start[i] = r;
        cursor[i] = r;
    }
}

__global__ void k_fill(const int* __restrict__ src, const int* __restrict__ dst,
                       int* __restrict__ cursor, int* __restrict__ csr, int n_edges) {
    for (int e = blockIdx.x * blockDim.x + threadIdx.x; e < n_edges; e += gridDim.x * blockDim.x) {
        int d = dst[e];
        int p = atomicAdd(&cursor[d], 1);
        csr[p] = src[e];
    }
}

// ---------------- mean aggregation (fp32 input) -> split hi/lo tables -------
// one 64-lane wave per node; lane owns features 2*lane, 2*lane+1
__global__ __launch_bounds__(256) void k_agg_f32(const float* __restrict__ feat,
                                                 const int* __restrict__ row_start,
                                                 const int* __restrict__ csr,
                                                 short* __restrict__ Mh,
                                                 short* __restrict__ Ml, int n_nodes) {
    int wave = (blockIdx.x * 256 + threadIdx.x) >> 6;
    if (wave >= n_nodes) return;
    int lane = threadIdx.x & 63;
    int s = row_start[wave], e = row_start[wave + 1];
    const float2* f2p = (const float2*)feat;
    float ax = 0.f, ay = 0.f;
    for (int j = s; j < e; ++j) {
        int nb = csr[j];
        float2 v = f2p[nb * 64 + lane];
        ax += v.x; ay += v.y;
    }
    float inv = (e > s) ? 1.0f / (float)(e - s) : 0.0f;
    float m0 = ax * inv, m1 = ay * inv;
    short h0 = f2bf(m0), l0 = f2bf(m0 - bf2f(h0));
    short h1 = f2bf(m1), l1 = f2bf(m1 - bf2f(h1));
    ((ushort2*)Mh)[wave * 64 + lane] = make_ushort2((unsigned short)h0, (unsigned short)h1);
    ((ushort2*)Ml)[wave * 64 + lane] = make_ushort2((unsigned short)l0, (unsigned short)l1);
}

// ---------------- mean aggregation from split hi/lo tables ----------------
__global__ __launch_bounds__(256) void k_agg_sp(const short* __restrict__ Fh,
                                                const short* __restrict__ Fl,
                                                const int* __restrict__ row_start,
                                                const int* __restrict__ csr,
                                                short* __restrict__ Mh,
                                                short* __restrict__ Ml, int n_nodes) {
    int wave = (blockIdx.x * 256 + threadIdx.x) >> 6;
    if (wave >= n_nodes) return;
    int lane = threadIdx.x & 63;
    int s = row_start[wave], e = row_start[wave + 1];
    const ushort2* fh = (const ushort2*)Fh;
    const ushort2* fl = (const ushort2*)Fl;
    float ax = 0.f, ay = 0.f;
    for (int j = s; j < e; ++j) {
        int nb = csr[j];
        ushort2 qh = fh[nb * 64 + lane];
        ushort2 ql = fl[nb * 64 + lane];
        ax += bf2f((short)qh.x) + bf2f((short)ql.x);
        ay += bf2f((short)qh.y) + bf2f((short)ql.y);
    }
    float inv = (e > s) ? 1.0f / (float)(e - s) : 0.0f;
    float m0 = ax * inv, m1 = ay * inv;
    short h0 = f2bf(m0), l0 = f2bf(m0 - bf2f(h0));
    short h1 = f2bf(m1), l1 = f2bf(m1 - bf2f(h1));
    ((ushort2*)Mh)[wave * 64 + lane] = make_ushort2((unsigned short)h0, (unsigned short)h1);
    ((ushort2*)Ml)[wave * 64 + lane] = make_ushort2((unsigned short)l0, (unsigned short)l1);
}

// ---------------- SAGE conv via split-bf16 MFMA (lean staging) --------------
// 32 nodes/block, 256 thr (4 waves x 2 ntiles). A=[mean|root] K=256 (8 ksteps).
// LDS row = 264 shorts (33 slots of 16B, odd -> bank-balanced).
__global__ __launch_bounds__(256, 4) void k_convm(
    const short* __restrict__ Mh, const short* __restrict__ Ml,
    const short* __restrict__ Rh, const short* __restrict__ Rl,
    const short* __restrict__ Bh, const short* __restrict__ Bl,
    const float* __restrict__ bias, short* __restrict__ Oh, short* __restrict__ Ol,
    int n_nodes) {
    __shared__ __align__(16) short Ah[32][264];
    __shared__ __align__(16) short Al[32][264];
    int tid = threadIdx.x;
    int node0 = blockIdx.x * 32;
    const s16x8* Mh8 = (const s16x8*)Mh;
    const s16x8* Ml8 = (const s16x8*)Ml;
    const s16x8* Rh8 = (const s16x8*)Rh;
    const s16x8* Rl8 = (const s16x8*)Rl;
    for (int i = tid; i < 32 * 32; i += 256) {
        int row = i >> 5, grp = i & 31;
        int node = node0 + row;
        s16x8 vh = (s16x8)0, vl = (s16x8)0;
        if (node < n_nodes) {
            vh = (grp < 16) ? Mh8[node * 16 + grp] : Rh8[node * 16 + (grp - 16)];
            vl = (grp < 16) ? Ml8[node * 16 + grp] : Rl8[node * 16 + (grp - 16)];
        }
        *(s16x8*)&Ah[row][grp * 8] = vh;
        *(s16x8*)&Al[row][grp * 8] = vl;
    }
    __syncthreads();

    int lane = tid & 63;
    int w = tid >> 6;
    int rowid = lane & 15;
    int g = lane >> 4;
    int t0 = w * 2;

    f32x4 acc[2][2];
    acc[0][0] = (f32x4)0.f; acc[0][1] = (f32x4)0.f;
    acc[1][0] = (f32x4)0.f; acc[1][1] = (f32x4)0.f;

    const bf16x8* Bh8 = (const bf16x8*)Bh;
    const bf16x8* Bl8 = (const bf16x8*)Bl;
    bf16x8 bh0 = Bh8[t0 * 64 + lane];
    bf16x8 bh1 = Bh8[(t0 + 1) * 64 + lane];
    bf16x8 bl0 = Bl8[t0 * 64 + lane];
    bf16x8 bl1 = Bl8[(t0 + 1) * 64 + lane];

    #pragma unroll
    for (int s = 0; s < 8; ++s) {
        bf16x8 nh0 = bh0, nh1 = bh1, nl0 = bl0, nl1 = bl1;
        if (s < 7) {
            nh0 = Bh8[((s + 1) * 8 + t0) * 64 + lane];
            nh1 = Bh8[((s + 1) * 8 + t0 + 1) * 64 + lane];
            nl0 = Bl8[((s + 1) * 8 + t0) * 64 + lane];
            nl1 = Bl8[((s + 1) * 8 + t0 + 1) * 64 + lane];
        }
        int kf = s * 32 + g * 8;
        bf16x8 a_h[2], a_l[2];
        #pragma unroll
        for (int m = 0; m < 2; ++m) {
            a_h[m] = *(const bf16x8*)&Ah[m * 16 + rowid][kf];
            a_l[m] = *(const bf16x8*)&Al[m * 16 + rowid][kf];
        }
        #pragma unroll
        for (int m = 0; m < 2; ++m) {
            acc[m][0] = __builtin_amdgcn_mfma_f32_16x16x32_bf16(a_h[m], bh0, acc[m][0], 0, 0, 0);
            acc[m][1] = __builtin_amdgcn_mfma_f32_16x16x32_bf16(a_h[m], bh1, acc[m][1], 0, 0, 0);
            acc[m][0] = __builtin_amdgcn_mfma_f32_16x16x32_bf16(a_l[m], bh0, acc[m][0], 0, 0, 0);
            acc[m][1] = __builtin_amdgcn_mfma_f32_16x16x32_bf16(a_l[m], bh1, acc[m][1], 0, 0, 0);
            acc[m][0] = __builtin_amdgcn_mfma_f32_16x16x32_bf16(a_h[m], bl0, acc[m][0], 0, 0, 0);
            acc[m][1] = __builtin_amdgcn_mfma_f32_16x16x32_bf16(a_h[m], bl1, acc[m][1], 0, 0, 0);
        }
        bh0 = nh0; bh1 = nh1; bl0 = nl0; bl1 = nl1;
    }

    // epilogue: relu(D + b) -> hi/lo tables
    int n0 = w * 32 + rowid;
    int n1 = n0 + 16;
    float b_0 = bias[n0], b_1 = bias[n1];
    unsigned short* OhU = (unsigned short*)Oh;
    unsigned short* OlU = (unsigned short*)Ol;
    #pragma unroll
    for (int m = 0; m < 2; ++m) {
        int node = node0 + m * 16 + g * 4;
        #pragma unroll
        for (int r = 0; r < 4; ++r) {
            if (node + r < n_nodes) {
                float v0 = fmaxf(acc[m][0][r] + b_0, 0.f);
                float v1 = fmaxf(acc[m][1][r] + b_1, 0.f);
                short h0 = f2bf(v0), l0 = f2bf(v0 - bf2f(h0));
                short h1 = f2bf(v1), l1 = f2bf(v1 - bf2f(h1));
                OhU[(node + r) * 128 + n0] = (unsigned short)h0;
                OlU[(node + r) * 128 + n0] = (unsigned short)l0;
                OhU[(node + r) * 128 + n1] = (unsigned short)h1;
                OlU[(node + r) * 128 + n1] = (unsigned short)l1;
            }
        }
    }
}

// ---------------- UV GEMM: [U|V] = h2 @ [Wm1_s; Wm1_d]^T (K=128) -----------
// 32 nodes/block, 256 thr; wave owns 4 ntiles (64 cols). fp32 out.
__global__ __launch_bounds__(256, 4) void k_guv(
    const short* __restrict__ H2h, const short* __restrict__ H2l,
    const short* __restrict__ Bh, const short* __restrict__ Bl,
    float* __restrict__ U, float* __restrict__ V, int n_nodes) {
    __shared__ __align__(16) short Ah[32][136];   // 17 slots of 16B (odd)
    __shared__ __align__(16) short Al[32][136];
    int tid = threadIdx.x;
    int node0 = blockIdx.x * 32;
    const s16x8* Hh8 = (const s16x8*)H2h;
    const s16x8* Hl8 = (const s16x8*)H2l;
    for (int i = tid; i < 32 * 16; i += 256) {
        int row = i >> 4, grp = i & 15;
        int node = node0 + row;
        s16x8 vh = (s16x8)0, vl = (s16x8)0;
        if (node < n_nodes) {
            vh = Hh8[node * 16 + grp];
            vl = Hl8[node * 16 + grp];
        }
        *(s16x8*)&Ah[row][grp * 8] = vh;
        *(s16x8*)&Al[row][grp * 8] = vl;
    }
    __syncthreads();

    int lane = tid & 63;
    int w = tid >> 6;
    int rowid = lane & 15;
    int g = lane >> 4;
    int t0 = w * 4;

    f32x4 acc[2][4];
    #pragma unroll
    for (int m = 0; m < 2; ++m)
        #pragma unroll
        for (int q = 0; q < 4; ++q) acc[m][q] = (f32x4)0.f;

    const bf16x8* Bh8 = (const bf16x8*)Bh;
    const bf16x8* Bl8 = (const bf16x8*)Bl;

    #pragma unroll
    for (int s = 0; s < 4; ++s) {
        bf16x8 bh[4], bl[4];
        #pragma unroll
        for (int q = 0; q < 4; ++q) {
            bh[q] = Bh8[(s * 16 + t0 + q) * 64 + lane];
            bl[q] = Bl8[(s * 16 + t0 + q) * 64 + lane];
        }
        int kf = s * 32 + g * 8;
        bf16x8 a_h[2], a_l[2];
        #pragma unroll
        for (int m = 0; m < 2; ++m) {
            a_h[m] = *(const bf16x8*)&Ah[m * 16 + rowid][kf];
            a_l[m] = *(const bf16x8*)&Al[m * 16 + rowid][kf];
        }
        #pragma unroll
        for (int m = 0; m < 2; ++m) {
            #pragma unroll
            for (int q = 0; q < 4; ++q) {
                acc[m][q] = __builtin_amdgcn_mfma_f32_16x16x32_bf16(a_h[m], bh[q], acc[m][q], 0, 0, 0);
                acc[m][q] = __builtin_amdgcn_mfma_f32_16x16x32_bf16(a_l[m], bh[q], acc[m][q], 0, 0, 0);
                acc[m][q] = __builtin_amdgcn_mfma_f32_16x16x32_bf16(a_h[m], bl[q], acc[m][q], 0, 0, 0);
            }
        }
    }

    // epilogue: cols n' = w*64 + q*16 + rowid; n'<128 -> U, else V (wave-uniform)
    float* dstbase = (w < 2) ? U : V;
    int cb = (w & 1) * 64 + rowid;
    #pragma unroll
    for (int m = 0; m < 2; ++m) {
        int node = node0 + m * 16 + g * 4;
        #pragma unroll
        for (int q = 0; q < 4; ++q) {
            int col = cb + q * 16;
            #pragma unroll
            for (int r = 0; r < 4; ++r) {
                if (node + r < n_nodes)
                    dstbase[(node + r) * 128 + col] = acc[m][q][r];
            }
        }
    }
}

// ---------------- streaming edge kernel ----------------
// one wave per edge (grid-stride): out = wm2 . relu(U[s] + V[d] + Wa@attr + bm1) + bm2
__global__ __launch_bounds__(256) void k_edge(
    const float* __restrict__ U, const float* __restrict__ V,
    const int* __restrict__ ps, const int* __restrict__ pd,
    const float* __restrict__ attr, const float* __restrict__ Wm1,
    const float* __restrict__ bm1, const float* __restrict__ wm2,
    const float* __restrict__ bm2, float* __restrict__ outp, int n_edges) {
    int lane = threadIdx.x & 63;
    int wid = (blockIdx.x * 256 + threadIdx.x) >> 6;
    int nw = (gridDim.x * 256) >> 6;

    int j0 = 2 * lane;
    // hoist attr-columns of Wm1 (Wa[j][k] = Wm1[j*272 + 256 + k]) for j0, j0+1
    float wa0[16], wa1[16];
    #pragma unroll
    for (int k4 = 0; k4 < 4; ++k4) {
        float4 t = *(const float4*)&Wm1[j0 * 272 + 256 + k4 * 4];
        wa0[k4 * 4 + 0] = t.x; wa0[k4 * 4 + 1] = t.y; wa0[k4 * 4 + 2] = t.z; wa0[k4 * 4 + 3] = t.w;
        float4 u = *(const float4*)&Wm1[(j0 + 1) * 272 + 256 + k4 * 4];
        wa1[k4 * 4 + 0] = u.x; wa1[k4 * 4 + 1] = u.y; wa1[k4 * 4 + 2] = u.z; wa1[k4 * 4 + 3] = u.w;
    }
    float bb0 = bm1[j0], bb1 = bm1[j0 + 1];
    float wm0 = wm2[j0], wm1v = wm2[j0 + 1];
    float bm2v = bm2[0];

    const float2* U2 = (const float2*)U;
    const float2* V2 = (const float2*)V;
    const float4* at4 = (const float4*)attr;

    for (int e = wid; e < n_edges; e += nw) {
        int s = ps[e];
        int d = pd[e];
        float2 u = U2[s * 64 + lane];
        float2 v = V2[d * 64 + lane];
        float4 a0 = at4[e * 4 + 0];
        float4 a1 = at4[e * 4 + 1];
        float4 a2 = at4[e * 4 + 2];
        float4 a3 = at4[e * 4 + 3];
        float av[16] = {a0.x, a0.y, a0.z, a0.w, a1.x, a1.y, a1.z, a1.w,
                        a2.x, a2.y, a2.z, a2.w, a3.x, a3.y, a3.z, a3.w};
        float t0 = 0.f, t1 = 0.f;
        #pragma unroll
        for (int k = 0; k < 16; ++k) {
            t0 += wa0[k] * av[k];
            t1 += wa1[k] * av[k];
        }
        float p = fmaxf(u.x + v.x + t0 + bb0, 0.f) * wm0
                + fmaxf(u.y + v.y + t1 + bb1, 0.f) * wm1v;
        p += __shfl_xor(p, 32, 64);
        p += __shfl_xor(p, 16, 64);
        p += __shfl_xor(p, 8, 64);
        p += __shfl_xor(p, 4, 64);
        p += __shfl_xor(p, 2, 64);
        p += __shfl_xor(p, 1, 64);
        if (lane == 0) outp[e] = p + bm2v;
    }
}

extern "C" void kernel_launch(void* const* d_in, const int* in_sizes, int n_in,
                              void* d_out, int out_size, void* d_ws, size_t ws_size,
                              hipStream_t stream) {
    const float* x     = (const float*)d_in[0];
    const int*   mp    = (const int*)d_in[1];
    const int*   pe    = (const int*)d_in[2];
    const float* attr  = (const float*)d_in[3];
    const float* W1_l  = (const float*)d_in[4];
    const float* b1    = (const float*)d_in[5];
    const float* W1_r  = (const float*)d_in[6];
    const float* W2_l  = (const float*)d_in[7];
    const float* b2    = (const float*)d_in[8];
    const float* W2_r  = (const float*)d_in[9];
    const float* Wm1   = (const float*)d_in[10];
    const float* bm1   = (const float*)d_in[11];
    const float* Wm2   = (const float*)d_in[12];
    const float* bm2   = (const float*)d_in[13];
    float* out = (float*)d_out;

    const int n_nodes = in_sizes[0] / HIDDEN;   // 50000
    const int n_mp    = in_sizes[1] / 2;        // 800000
    const int n_pred  = in_sizes[2] / 2;        // 400000

    const int* mp_src = mp;
    const int* mp_dst = mp + n_mp;
    const int* p_src  = pe;
    const int* p_dst  = pe + n_pred;

    char* ws = (char*)d_ws;
    size_t off = 0;
    auto alloc = [&](size_t bytes) -> void* {
        void* p = ws + off;
        off += (bytes + 255) & ~(size_t)255;
        return p;
    };
    short* Wc1h = (short*)alloc(8 * 8 * 64 * 8 * sizeof(short));
    short* Wc1l = (short*)alloc(8 * 8 * 64 * 8 * sizeof(short));
    short* Wc2h = (short*)alloc(8 * 8 * 64 * 8 * sizeof(short));
    short* Wc2l = (short*)alloc(8 * 8 * 64 * 8 * sizeof(short));
    short* Buvh = (short*)alloc(4 * 16 * 64 * 8 * sizeof(short));
    short* Buvl = (short*)alloc(4 * 16 * 64 * 8 * sizeof(short));
    int*   deg    = (int*)alloc((size_t)n_nodes * sizeof(int));
    int*   rowst  = (int*)alloc(((size_t)n_nodes + 1) * sizeof(int));
    int*   cursor = (int*)alloc((size_t)n_nodes * sizeof(int));
    int*   part   = (int*)alloc(64 * sizeof(int));
    int*   csr    = (int*)alloc((size_t)n_mp * sizeof(int));
    short* Xh  = (short*)alloc((size_t)n_nodes * HIDDEN * sizeof(short));
    short* Xl  = (short*)alloc((size_t)n_nodes * HIDDEN * sizeof(short));
    short* Mh  = (short*)alloc((size_t)n_nodes * HIDDEN * sizeof(short));
    short* Ml  = (short*)alloc((size_t)n_nodes * HIDDEN * sizeof(short));
    short* H1h = (short*)alloc((size_t)n_nodes * HIDDEN * sizeof(short));
    short* H1l = (short*)alloc((size_t)n_nodes * HIDDEN * sizeof(short));
    short* H2h = (short*)alloc((size_t)n_nodes * HIDDEN * sizeof(short));
    short* H2l = (short*)alloc((size_t)n_nodes * HIDDEN * sizeof(short));
    float* Ubuf = (float*)alloc((size_t)n_nodes * HIDDEN * sizeof(float));
    float* Vbuf = (float*)alloc((size_t)n_nodes * HIDDEN * sizeof(float));
    (void)ws_size; (void)n_in; (void)out_size;

    const int P = (n_nodes + 1023) / 1024;   // 49 partial blocks (<=64)

    hipMemsetAsync(deg, 0, (size_t)n_nodes * sizeof(int), stream);

    // weight packing + x split
    k_packw_conv<<<16, 256, 0, stream>>>(W1_l, W1_r, Wc1h, Wc1l);
    k_packw_conv<<<16, 256, 0, stream>>>(W2_l, W2_r, Wc2h, Wc2l);
    k_packw_uv<<<16, 256, 0, stream>>>(Wm1, Buvh, Buvl);
    k_split<<<(n_nodes * 32 + 255) / 256, 256, 0, stream>>>(x, Xh, Xl, n_nodes * 32);

    // CSR build
    k_deg<<<(n_mp + 255) / 256, 256, 0, stream>>>(mp_dst, deg, n_mp);
    k_scan_blk<<<P, 1024, 0, stream>>>(deg, rowst, part, n_nodes);
    k_scan_top<<<1, 64, 0, stream>>>(part, rowst, P, n_nodes);
    k_scan_add<<<P, 1024, 0, stream>>>(rowst, cursor, part, n_nodes);
    k_fill<<<(n_mp + 255) / 256, 256, 0, stream>>>(mp_src, mp_dst, cursor, csr, n_mp);

    // conv1
    k_agg_f32<<<(n_nodes + 3) / 4, 256, 0, stream>>>(x, rowst, csr, Mh, Ml, n_nodes);
    k_convm<<<(n_nodes + 31) / 32, 256, 0, stream>>>(Mh, Ml, Xh, Xl, Wc1h, Wc1l, b1,
                                                     H1h, H1l, n_nodes);
    // conv2
    k_agg_sp<<<(n_nodes + 3) / 4, 256, 0, stream>>>(H1h, H1l, rowst, csr, Mh, Ml, n_nodes);
    k_convm<<<(n_nodes + 31) / 32, 256, 0, stream>>>(Mh, Ml, H1h, H1l, Wc2h, Wc2l, b2,
                                                     H2h, H2l, n_nodes);

    // UV GEMM + streaming edge MLP
    k_guv<<<(n_nodes + 31) / 32, 256, 0, stream>>>(H2h, H2l, Buvh, Buvl, Ubuf, Vbuf, n_nodes);
    k_edge<<<2048, 256, 0, stream>>>(Ubuf, Vbuf, p_src, p_dst, attr, Wm1,
                                     bm1, Wm2, bm2, out, n_pred);
}